// Round 1
// baseline (11645.792 us; speedup 1.0000x reference)
//
#include <hip/hip_runtime.h>

typedef __attribute__((ext_vector_type(8))) short bf16x8;
typedef __attribute__((ext_vector_type(4))) float f32x4;

#define T_LEN 256
#define OFF_W1  0
#define OFF_W2  8192
#define OFF_W3  24576
#define OFF_WU1 32768
#define OFF_WR1 49152
#define OFF_WN1 65536
#define OFF_WU2 81920
#define OFF_WR2 90112
#define OFF_WN2 98304
#define PACK_TOT 114688

__device__ __forceinline__ unsigned short bf16r(float f){
  unsigned int x = __builtin_bit_cast(unsigned int, f);
  unsigned int r = (x + 0x7FFFu + ((x >> 16) & 1u)) >> 16;
  return (unsigned short)r;
}
__device__ __forceinline__ float bf16tof(unsigned short u){
  unsigned int v = ((unsigned int)u) << 16;
  return __builtin_bit_cast(float, v);
}
__device__ __forceinline__ float fast_tanh(float x){
  float e = __expf(2.0f * x);
  return 1.0f - 2.0f * __builtin_amdgcn_rcpf(1.0f + e);
}
__device__ __forceinline__ float fast_sigmoid(float x){
  return __builtin_amdgcn_rcpf(1.0f + __expf(-x));
}
__device__ __forceinline__ f32x4 mfma16(bf16x8 a, bf16x8 b, f32x4 c){
  return __builtin_amdgcn_mfma_f32_16x16x32_bf16(a, b, c, 0, 0, 0);
}
// Packed B-fragment: block = ntile*(K/32)+kstep; lane's 8 bf16 contiguous.
__device__ __forceinline__ bf16x8 load_bfrag(const unsigned short* p, int blk, int lane){
  return *reinterpret_cast<const bf16x8*>(p + ((blk << 6) + lane) * 8);
}
// A-fragment read from a [16][128] bf16 LDS tile, XOR-swizzled (T2/G4).
__device__ __forceinline__ bf16x8 lds_readA(const unsigned short* buf, int lane, int ks){
  int row = lane & 15;
  int k0 = (ks << 5) + ((lane >> 4) << 3);
  return *reinterpret_cast<const bf16x8*>(buf + row * 128 + (k0 ^ (row << 3)));
}
// Write one MFMA C/D fragment (rows (lane>>4)*4+i, col colbase+(lane&15)) as bf16.
__device__ __forceinline__ void lds_writeC(unsigned short* buf, int lane, int colbase, f32x4 v){
  int rb = (lane >> 4) << 2;
  int c  = colbase + (lane & 15);
#pragma unroll
  for (int i = 0; i < 4; ++i){
    int r = rb + i;
    buf[r * 128 + (c ^ (r << 3))] = bf16r(v[i]);
  }
}
// hi/lo split write (state GEMM inputs): v = hi + lo, both bf16.
__device__ __forceinline__ void lds_writeSplit(unsigned short* bh, unsigned short* bl,
                                               int lane, int colbase, f32x4 v){
  int rb = (lane >> 4) << 2;
  int c  = colbase + (lane & 15);
#pragma unroll
  for (int i = 0; i < 4; ++i){
    int r = rb + i;
    int idx = r * 128 + (c ^ (r << 3));
    unsigned short h = bf16r(v[i]);
    bh[idx] = h;
    bl[idx] = bf16r(v[i] - bf16tof(h));
  }
}

struct RkW {
  bf16x8 w1[2][2]; // [tile(2w+t)][kstep]
  bf16x8 w2[2][4];
  bf16x8 w3[4];
};

// One ode_f evaluation: k = W3^T tanh(W2^T tanh(W1^T y + b1) + b2) + b3  (row-vector form)
__device__ __forceinline__ f32x4 ode_eval(f32x4 yin,
    unsigned short* SA, unsigned short* SB, unsigned short* SC,
    const RkW& W, float b1c0, float b1c1, float b2c0, float b2c1, float b3c,
    int lane, int w)
{
  lds_writeC(SA, lane, w << 4, yin);
  __syncthreads();
  f32x4 a0 = {0.f,0.f,0.f,0.f}, a1 = {0.f,0.f,0.f,0.f};
#pragma unroll
  for (int ks = 0; ks < 2; ++ks){
    bf16x8 af = lds_readA(SA, lane, ks);
    a0 = mfma16(af, W.w1[0][ks], a0);
    a1 = mfma16(af, W.w1[1][ks], a1);
  }
#pragma unroll
  for (int i = 0; i < 4; ++i){ a0[i] = fast_tanh(a0[i] + b1c0); a1[i] = fast_tanh(a1[i] + b1c1); }
  lds_writeC(SB, lane, w << 5, a0);
  lds_writeC(SB, lane, (w << 5) + 16, a1);
  __syncthreads();
  f32x4 c0 = {0.f,0.f,0.f,0.f}, c1 = {0.f,0.f,0.f,0.f};
#pragma unroll
  for (int ks = 0; ks < 4; ++ks){
    bf16x8 af = lds_readA(SB, lane, ks);
    c0 = mfma16(af, W.w2[0][ks], c0);
    c1 = mfma16(af, W.w2[1][ks], c1);
  }
#pragma unroll
  for (int i = 0; i < 4; ++i){ c0[i] = fast_tanh(c0[i] + b2c0); c1[i] = fast_tanh(c1[i] + b2c1); }
  lds_writeC(SC, lane, w << 5, c0);
  lds_writeC(SC, lane, (w << 5) + 16, c1);
  __syncthreads();
  f32x4 k = {0.f,0.f,0.f,0.f};
#pragma unroll
  for (int ks = 0; ks < 4; ++ks){
    bf16x8 af = lds_readA(SC, lane, ks);
    k = mfma16(af, W.w3[ks], k);
  }
#pragma unroll
  for (int i = 0; i < 4; ++i) k[i] += b3c;
  return k;
}

// GRU first layer: tanh([state_hi+state_lo]@Wx1[0:128] + b + x*Wx1[128]) -> SBo
__device__ __forceinline__ void gru_g1(const unsigned short* Ah, const unsigned short* Al,
    const unsigned short* pack, int pb,
    float bc0, float bc1, float wl0, float wl1, const float* xr,
    int lane, int w, unsigned short* SBo)
{
  f32x4 a0 = {0.f,0.f,0.f,0.f}, a1 = {0.f,0.f,0.f,0.f};
#pragma unroll
  for (int ks = 0; ks < 4; ++ks){
    bf16x8 ah  = lds_readA(Ah, lane, ks);
    bf16x8 al  = lds_readA(Al, lane, ks);
    bf16x8 b0  = load_bfrag(pack + pb, ((2 * w) << 2) + ks, lane);
    bf16x8 b1v = load_bfrag(pack + pb, ((2 * w + 1) << 2) + ks, lane);
    a0 = mfma16(al, b0, a0);  a0 = mfma16(ah, b0, a0);
    a1 = mfma16(al, b1v, a1); a1 = mfma16(ah, b1v, a1);
  }
#pragma unroll
  for (int i = 0; i < 4; ++i){
    a0[i] = fast_tanh(a0[i] + bc0 + xr[i] * wl0);
    a1[i] = fast_tanh(a1[i] + bc1 + xr[i] * wl1);
  }
  lds_writeC(SBo, lane, w << 5, a0);
  lds_writeC(SBo, lane, (w << 5) + 16, a1);
}

__device__ __forceinline__ f32x4 gru_g2(const unsigned short* Sin, const unsigned short* pack,
                                        int pb, int nt, int lane){
  f32x4 a = {0.f,0.f,0.f,0.f};
#pragma unroll
  for (int ks = 0; ks < 4; ++ks){
    bf16x8 af = lds_readA(Sin, lane, ks);
    bf16x8 bf = load_bfrag(pack + pb, (nt << 2) + ks, lane);
    a = mfma16(af, bf, a);
  }
  return a;
}

// Pack all weight matrices to bf16 in MFMA B-fragment order.
__global__ void prep_pack(const float* __restrict__ W1, const float* __restrict__ W2,
                          const float* __restrict__ W3, const float* __restrict__ Wu1,
                          const float* __restrict__ Wr1, const float* __restrict__ Wn1,
                          const float* __restrict__ Wu2, const float* __restrict__ Wr2,
                          const float* __restrict__ Wn2, unsigned short* __restrict__ pack)
{
  int e = blockIdx.x * blockDim.x + threadIdx.x;
  if (e >= PACK_TOT) return;
  const int offs[10] = {0, 8192, 24576, 32768, 49152, 65536, 81920, 90112, 98304, 114688};
  const int Ks[9] = {64,128,128,128,128,128,128,128,128};
  const int Ns[9] = {128,128,64,128,128,128,64,64,128};
  const float* srcs[9] = {W1, W2, W3, Wu1, Wr1, Wn1, Wu2, Wr2, Wn2};
  int m = 0;
  while (e >= offs[m + 1]) ++m;
  int el = e - offs[m];
  int j = el & 7, lane = (el >> 3) & 63, blk = el >> 9;
  int ksteps = Ks[m] >> 5;
  int ks = blk % ksteps, nt = blk / ksteps;
  int k = ks * 32 + ((lane >> 4) << 3) + j;
  int n = nt * 16 + (lane & 15);
  pack[e] = bf16r(srcs[m][k * Ns[m] + n]);
}

__global__ __launch_bounds__(256, 2) void ode_rnn_main(
  const float* __restrict__ bts, const float* __restrict__ mtr,
  const float* __restrict__ b1, const float* __restrict__ b2, const float* __restrict__ b3,
  const float* __restrict__ bu1, const float* __restrict__ bu2,
  const float* __restrict__ br1, const float* __restrict__ br2,
  const float* __restrict__ bn1, const float* __restrict__ bn2,
  const float* __restrict__ Wu1f, const float* __restrict__ Wr1f, const float* __restrict__ Wn1f,
  const unsigned short* __restrict__ pack, float* __restrict__ out)
{
  __shared__ unsigned short SA[2048], SB[2048], SC[2048], SD[2048];
  const int tid = threadIdx.x, w = tid >> 6, lane = tid & 63;
  const int col16 = lane & 15, rbase = (lane >> 4) << 2;
  const int rowBase = blockIdx.x * 16;

  // RK4 weight fragments in registers (per-wave N-chunk)
  RkW W;
#pragma unroll
  for (int t = 0; t < 2; ++t){
#pragma unroll
    for (int ks = 0; ks < 2; ++ks) W.w1[t][ks] = load_bfrag(pack + OFF_W1, (2 * w + t) * 2 + ks, lane);
#pragma unroll
    for (int ks = 0; ks < 4; ++ks) W.w2[t][ks] = load_bfrag(pack + OFF_W2, (2 * w + t) * 4 + ks, lane);
  }
#pragma unroll
  for (int ks = 0; ks < 4; ++ks) W.w3[ks] = load_bfrag(pack + OFF_W3, w * 4 + ks, lane);

  const int cA0 = (w << 5) + col16, cA1 = (w << 5) + 16 + col16, cB = (w << 4) + col16;
  const float b1c0 = b1[cA0], b1c1 = b1[cA1];
  const float b2c0 = b2[cA0], b2c1 = b2[cA1];
  const float b3c  = b3[cB];
  const float bu1c0 = bu1[cA0], bu1c1 = bu1[cA1], bu2c = bu2[cB];
  const float br1c0 = br1[cA0], br1c1 = br1[cA1], br2c = br2[cB];
  const float bn1c0 = bn1[cA0], bn1c1 = bn1[cA1];
  const float bn2c0 = bn2[cB], bn2c1 = bn2[64 + cB];
  const float wu1L0 = Wu1f[16384 + cA0], wu1L1 = Wu1f[16384 + cA1];
  const float wr1L0 = Wr1f[16384 + cA0], wr1L1 = Wr1f[16384 + cA1];
  const float wn1L0 = Wn1f[16384 + cA0], wn1L1 = Wn1f[16384 + cA1];

  f32x4 me = {0.f,0.f,0.f,0.f}, sd = {0.f,0.f,0.f,0.f};

#pragma unroll 1
  for (int s = 0; s < T_LEN; ++s){
    const int tj = T_LEN - 1 - s;
    const float t1 = bts[2 * tj];
    const float t0 = (s == 0) ? 5.0f : bts[2 * tj + 2];
    const float hh = (t1 - t0) * 0.125f;

    float xr[4], mk[4];
#pragma unroll
    for (int i = 0; i < 4; ++i){
      int r = rowBase + rbase + i;
      xr[i] = bts[(r * T_LEN + tj) * 2 + 1];
      mk[i] = mtr[r * T_LEN + tj];
    }

    // ---------------- RK4 (8 substeps) ----------------
    f32x4 y0 = me;
#pragma unroll 1
    for (int ss = 0; ss < 8; ++ss){
      f32x4 ksum = {0.f,0.f,0.f,0.f}, kp = {0.f,0.f,0.f,0.f};
#pragma unroll 1
      for (int st = 0; st < 4; ++st){
        float ac = (st == 0) ? 0.0f : ((st == 3) ? hh : 0.5f * hh);
        f32x4 yin = y0 + ac * kp;
        f32x4 k = ode_eval(yin, SA, SB, SC, W, b1c0, b1c1, b2c0, b2c1, b3c, lane, w);
        float wgt = (st == 1 || st == 2) ? 2.0f : 1.0f;
        ksum += wgt * k;
        kp = k;
      }
      y0 += (hh * (1.0f / 6.0f)) * ksum;
    }
    // y0 = mean_ode (fp32, never rounded in place)

    // ---------------- GRU ----------------
    lds_writeSplit(SA, SD, lane, w << 4, y0);
    lds_writeSplit(SA, SD, lane, 64 + (w << 4), sd);
    __syncthreads();                                          // g1
    gru_g1(SA, SD, pack, OFF_WU1, bu1c0, bu1c1, wu1L0, wu1L1, xr, lane, w, SB);
    __syncthreads();                                          // g2
    f32x4 uac = gru_g2(SB, pack, OFF_WU2, w, lane);
    f32x4 ug;
#pragma unroll
    for (int i = 0; i < 4; ++i) ug[i] = fast_sigmoid(uac[i] + bu2c);
    __syncthreads();                                          // g3 (SB reads done before r-path writes)
    gru_g1(SA, SD, pack, OFF_WR1, br1c0, br1c1, wr1L0, wr1L1, xr, lane, w, SB);
    __syncthreads();                                          // g4
    f32x4 rac = gru_g2(SB, pack, OFF_WR2, w, lane);
    f32x4 ycm, ycs;
#pragma unroll
    for (int i = 0; i < 4; ++i){
      float rg = fast_sigmoid(rac[i] + br2c);
      ycm[i] = y0[i] * rg;
      ycs[i] = sd[i] * rg;
    }
    lds_writeSplit(SA, SD, lane, w << 4, ycm);                // safe: SA/SD reads done before g4
    lds_writeSplit(SA, SD, lane, 64 + (w << 4), ycs);
    __syncthreads();                                          // g5
    gru_g1(SA, SD, pack, OFF_WN1, bn1c0, bn1c1, wn1L0, wn1L1, xr, lane, w, SB);
    __syncthreads();                                          // g6
    f32x4 n0 = {0.f,0.f,0.f,0.f}, n1 = {0.f,0.f,0.f,0.f};
#pragma unroll
    for (int ks = 0; ks < 4; ++ks){
      bf16x8 af  = lds_readA(SB, lane, ks);
      bf16x8 bf0 = load_bfrag(pack + OFF_WN2, (w << 2) + ks, lane);
      bf16x8 bf1 = load_bfrag(pack + OFF_WN2, ((4 + w) << 2) + ks, lane);
      n0 = mfma16(af, bf0, n0);
      n1 = mfma16(af, bf1, n1);
    }
#pragma unroll
    for (int i = 0; i < 4; ++i){
      float uu  = ug[i];
      float nm  = (1.f - uu) * (n0[i] + bn2c0) + uu * y0[i];
      float nsd = (1.f - uu) * (n1[i] + bn2c1) + uu * sd[i];
      float m   = mk[i];
      me[i] = m * nm + (1.f - m) * y0[i];
      float fs = m * nsd + (1.f - m) * sd[i];
      sd[i] = fabsf(fs);
    }
  }

  // ---------------- store (mean then std, concatenated) ----------------
#pragma unroll
  for (int i = 0; i < 4; ++i){
    int r = rowBase + rbase + i;
    out[r * 64 + (w << 4) + col16] = me[i];
    out[524288 + r * 64 + (w << 4) + col16] = sd[i];
  }
}

extern "C" void kernel_launch(void* const* d_in, const int* in_sizes, int n_in,
                              void* d_out, int out_size, void* d_ws, size_t ws_size,
                              hipStream_t stream)
{
  (void)in_sizes; (void)n_in; (void)out_size; (void)ws_size;
  unsigned short* pack = (unsigned short*)d_ws;
  prep_pack<<<dim3(PACK_TOT / 256), dim3(256), 0, stream>>>(
      (const float*)d_in[2],  (const float*)d_in[4],  (const float*)d_in[6],
      (const float*)d_in[8],  (const float*)d_in[12], (const float*)d_in[16],
      (const float*)d_in[10], (const float*)d_in[14], (const float*)d_in[18],
      pack);
  ode_rnn_main<<<dim3(512), dim3(256), 0, stream>>>(
      (const float*)d_in[0],  (const float*)d_in[1],
      (const float*)d_in[3],  (const float*)d_in[5],  (const float*)d_in[7],
      (const float*)d_in[9],  (const float*)d_in[11],
      (const float*)d_in[13], (const float*)d_in[15],
      (const float*)d_in[17], (const float*)d_in[19],
      (const float*)d_in[8],  (const float*)d_in[12], (const float*)d_in[16],
      (const unsigned short*)pack, (float*)d_out);
}

// Round 2
// 11041.488 us; speedup vs baseline: 1.0547x; 1.0547x over previous
//
#include <hip/hip_runtime.h>

typedef __attribute__((ext_vector_type(8))) short bf16x8;
typedef __attribute__((ext_vector_type(4))) float f32x4;

#define T_LEN 256
// pack offsets (short units) — same layout as R1
#define OFF_W1  0
#define OFF_W2  8192
#define OFF_W3  24576
#define OFF_WU1 32768
#define OFF_WR1 49152
#define OFF_WN1 65536
#define OFF_WU2 81920
#define OFF_WR2 90112
#define OFF_WN2 98304
#define PACK_TOT 114688

// LDS layout (short units)
#define SA_O   0      // yin  [16][64]  bf16, swizzled
#define SB_O   1024   // h1 / gru h1(u,n) [16][128] bf16, swizzled
#define SC_O   3072   // h2   [16][128]
#define SE_O   5120   // gru h1(r) [16][128]
#define SGH_O  7168   // state hi [16][128]  (cols 0-63 mean, 64-127 std)
#define SGL_O  9216   // state lo [16][128]
#define FU_O   5632   // u gate f32 [16][64]  (float units; short 11264)
#define FR_O   6656   // r gate f32 [16][64]  (short 13312)
#define LDS_SHORTS 15360

__device__ __forceinline__ unsigned short bf16r(float f){
  unsigned int x = __builtin_bit_cast(unsigned int, f);
  unsigned int r = (x + 0x7FFFu + ((x >> 16) & 1u)) >> 16;
  return (unsigned short)r;
}
__device__ __forceinline__ float bf16tof(unsigned short u){
  unsigned int v = ((unsigned int)u) << 16;
  return __builtin_bit_cast(float, v);
}
__device__ __forceinline__ float fast_tanh(float x){
  float e = __builtin_amdgcn_exp2f(x * 2.885390081777927f);   // exp(2x)
  return 1.0f - 2.0f * __builtin_amdgcn_rcpf(1.0f + e);
}
__device__ __forceinline__ float fast_sigmoid(float x){
  float e = __builtin_amdgcn_exp2f(x * -1.4426950408889634f); // exp(-x)
  return __builtin_amdgcn_rcpf(1.0f + e);
}
__device__ __forceinline__ f32x4 mfma16(bf16x8 a, bf16x8 b, f32x4 c){
  return __builtin_amdgcn_mfma_f32_16x16x32_bf16(a, b, c, 0, 0, 0);
}
__device__ __forceinline__ bf16x8 load_bfrag(const unsigned short* p, int blk, int lane){
  return *reinterpret_cast<const bf16x8*>(p + ((blk << 6) + lane) * 8);
}
__device__ __forceinline__ bf16x8 ldsA(const unsigned short* LDSU, int idx){
  return *reinterpret_cast<const bf16x8*>(LDSU + idx);
}

// Pack all weight matrices to bf16 in MFMA B-fragment order (unchanged from R1).
__global__ void prep_pack(const float* __restrict__ W1, const float* __restrict__ W2,
                          const float* __restrict__ W3, const float* __restrict__ Wu1,
                          const float* __restrict__ Wr1, const float* __restrict__ Wn1,
                          const float* __restrict__ Wu2, const float* __restrict__ Wr2,
                          const float* __restrict__ Wn2, unsigned short* __restrict__ pack)
{
  int e = blockIdx.x * blockDim.x + threadIdx.x;
  if (e >= PACK_TOT) return;
  const int offs[10] = {0, 8192, 24576, 32768, 49152, 65536, 81920, 90112, 98304, 114688};
  const int Ks[9] = {64,128,128,128,128,128,128,128,128};
  const int Ns[9] = {128,128,64,128,128,128,64,64,128};
  const float* srcs[9] = {W1, W2, W3, Wu1, Wr1, Wn1, Wu2, Wr2, Wn2};
  int m = 0;
  while (e >= offs[m + 1]) ++m;
  int el = e - offs[m];
  int j = el & 7, lane = (el >> 3) & 63, blk = el >> 9;
  int ksteps = Ks[m] >> 5;
  int ks = blk % ksteps, nt = blk / ksteps;
  int k = ks * 32 + ((lane >> 4) << 3) + j;
  int n = nt * 16 + (lane & 15);
  pack[e] = bf16r(srcs[m][k * Ns[m] + n]);
}

__global__ __launch_bounds__(512, 4) void ode_rnn_main(
  const float* __restrict__ bts, const float* __restrict__ mtr,
  const float* __restrict__ b1, const float* __restrict__ b2, const float* __restrict__ b3,
  const float* __restrict__ bu1, const float* __restrict__ bu2,
  const float* __restrict__ br1, const float* __restrict__ br2,
  const float* __restrict__ bn1, const float* __restrict__ bn2,
  const float* __restrict__ Wu1f, const float* __restrict__ Wr1f, const float* __restrict__ Wn1f,
  const unsigned short* __restrict__ pack, float* __restrict__ out)
{
  __shared__ __align__(16) unsigned short LDSU[LDS_SHORTS];
  float* FUR = (float*)LDSU;
  const int tid = threadIdx.x, w = tid >> 6, lane = tid & 63;
  const int arow = lane & 15, g = lane >> 4, rb = g << 2;
  const int c128 = (w << 4) + arow;        // this wave's 128-wide tile column
  const int c64  = ((w & 3) << 4) + arow;  // this wave's 64-wide tile column
  const bool isMean = (w < 4);
  const int rowBase = blockIdx.x * 16;

  // precomputed per-lane LDS indices (short units / float units)
  int a128[4], a64v[2], wr128[4], wr64[4], furi[4];
#pragma unroll
  for (int ks = 0; ks < 4; ++ks) a128[ks] = arow*128 + ((32*ks + 8*g) ^ (arow << 3));
#pragma unroll
  for (int ks = 0; ks < 2; ++ks) a64v[ks] = arow*64 + ((32*ks + 8*g) ^ ((arow & 7) << 3));
#pragma unroll
  for (int i = 0; i < 4; ++i){
    int r = rb + i;
    wr128[i] = r*128 + (c128 ^ (r << 3));
    wr64[i]  = r*64  + (c64 ^ ((r & 7) << 3));
    furi[i]  = r*64 + c64;
  }

  // per-wave weight fragments (1 N-tile per layer)
  bf16x8 w1f[2], w2f[4], w3f[4];
#pragma unroll
  for (int ks = 0; ks < 2; ++ks) w1f[ks] = load_bfrag(pack + OFF_W1, 2*w + ks, lane);
#pragma unroll
  for (int ks = 0; ks < 4; ++ks) w2f[ks] = load_bfrag(pack + OFF_W2, 4*w + ks, lane);
#pragma unroll
  for (int ks = 0; ks < 4; ++ks) w3f[ks] = load_bfrag(pack + OFF_W3, 4*(w & 3) + ks, lane);

  const float b1c = b1[c128], b2c = b2[c128], b3c = b3[c64];
  const float bu1c = bu1[c128], br1c = br1[c128], bn1c = bn1[c128], bn2c = bn2[c128];
  const float g2b = isMean ? bu2[c64] : br2[c64];
  const float wu1L = Wu1f[16384 + c128], wr1L = Wr1f[16384 + c128], wn1L = Wn1f[16384 + c128];

  // zero initial yin (mean0 = 0)
  LDSU[SA_O + 2*tid] = 0;
  LDSU[SA_O + 2*tid + 1] = 0;

  f32x4 st = {0.f,0.f,0.f,0.f};   // w<4: mean; w>=4: std
  f32x4 y0 = {0.f,0.f,0.f,0.f};   // mean_ode (w<4)
  f32x4 u  = {0.f,0.f,0.f,0.f};

#pragma unroll 1
  for (int s = 0; s < T_LEN; ++s){
    const int tj = T_LEN - 1 - s;
    const float t1 = bts[2*tj];
    const float t0 = (s == 0) ? 5.0f : bts[2*tj + 2];
    const float hh = (t1 - t0) * 0.125f;

    f32x4 xr;
#pragma unroll
    for (int i = 0; i < 4; ++i) xr[i] = bts[((rowBase + rb + i) * T_LEN + tj) * 2 + 1];

    y0 = st;  // mean state enters RK4 (w<4)

    // ---------------- RK4: 8 substeps x 4 stages ----------------
#pragma unroll 1
    for (int ss = 0; ss < 8; ++ss){
      f32x4 ksum = {0.f,0.f,0.f,0.f};
#pragma unroll 1
      for (int stg = 0; stg < 4; ++stg){
        const bool lastEval = (ss == 7 && stg == 3);
        __syncthreads();                       // yin (SA) ready
        // P1: h1-tile w = tanh(yin @ W1 + b1)
        f32x4 h = {0.f,0.f,0.f,0.f};
        h = mfma16(ldsA(LDSU, SA_O + a64v[0]), w1f[0], h);
        h = mfma16(ldsA(LDSU, SA_O + a64v[1]), w1f[1], h);
#pragma unroll
        for (int i = 0; i < 4; ++i) h[i] = fast_tanh(h[i] + b1c);
#pragma unroll
        for (int i = 0; i < 4; ++i) LDSU[SB_O + wr128[i]] = bf16r(h[i]);
        __syncthreads();
        // P2: h2-tile w = tanh(h1 @ W2 + b2)
        f32x4 h2 = {0.f,0.f,0.f,0.f};
#pragma unroll
        for (int ks = 0; ks < 4; ++ks)
          h2 = mfma16(ldsA(LDSU, SB_O + a128[ks]), w2f[ks], h2);
#pragma unroll
        for (int i = 0; i < 4; ++i) h2[i] = fast_tanh(h2[i] + b2c);
#pragma unroll
        for (int i = 0; i < 4; ++i) LDSU[SC_O + wr128[i]] = bf16r(h2[i]);
        __syncthreads();
        // P3: waves 0-3 only: k-tile, RK4 update, write next yin (or state)
        if (isMean){
          f32x4 k = {0.f,0.f,0.f,0.f};
#pragma unroll
          for (int ks = 0; ks < 4; ++ks)
            k = mfma16(ldsA(LDSU, SC_O + a128[ks]), w3f[ks], k);
          const float wgt = (stg == 1 || stg == 2) ? 2.0f : 1.0f;
#pragma unroll
          for (int i = 0; i < 4; ++i){ k[i] += b3c; ksum[i] += wgt * k[i]; }
          if (stg < 3){
            const float ac = (stg == 2) ? hh : 0.5f * hh;
#pragma unroll
            for (int i = 0; i < 4; ++i){
              float yn = y0[i] + ac * k[i];
              LDSU[SA_O + wr64[i]] = bf16r(yn);
            }
          } else {
#pragma unroll
            for (int i = 0; i < 4; ++i) y0[i] += (hh * (1.0f/6.0f)) * ksum[i];
            if (!lastEval){
#pragma unroll
              for (int i = 0; i < 4; ++i) LDSU[SA_O + wr64[i]] = bf16r(y0[i]);
            } else {
#pragma unroll
              for (int i = 0; i < 4; ++i){   // state mean hi/lo
                unsigned short hi = bf16r(y0[i]);
                LDSU[SGH_O + wr128[i]] = hi;
                LDSU[SGL_O + wr128[i]] = bf16r(y0[i] - bf16tof(hi));
              }
            }
          }
        } else if (lastEval){
#pragma unroll
          for (int i = 0; i < 4; ++i){       // state std hi/lo
            unsigned short hi = bf16r(st[i]);
            LDSU[SGH_O + wr128[i]] = hi;
            LDSU[SGL_O + wr128[i]] = bf16r(st[i] - bf16tof(hi));
          }
        }
      }
    }

    // ---------------- GRU ----------------
    __syncthreads();   // state (SGH/SGL) ready
    // g1: u & r first layers (each wave: its 16-col tile of both)
    {
      f32x4 au = {0.f,0.f,0.f,0.f}, ar = {0.f,0.f,0.f,0.f};
#pragma unroll
      for (int ks = 0; ks < 4; ++ks){
        bf16x8 ah = ldsA(LDSU, SGH_O + a128[ks]);
        bf16x8 al = ldsA(LDSU, SGL_O + a128[ks]);
        bf16x8 bu = load_bfrag(pack + OFF_WU1, 4*w + ks, lane);
        bf16x8 br = load_bfrag(pack + OFF_WR1, 4*w + ks, lane);
        au = mfma16(al, bu, au); au = mfma16(ah, bu, au);
        ar = mfma16(al, br, ar); ar = mfma16(ah, br, ar);
      }
#pragma unroll
      for (int i = 0; i < 4; ++i){
        au[i] = fast_tanh(au[i] + bu1c + xr[i] * wu1L);
        ar[i] = fast_tanh(ar[i] + br1c + xr[i] * wr1L);
      }
#pragma unroll
      for (int i = 0; i < 4; ++i){
        LDSU[SB_O + wr128[i]] = bf16r(au[i]);
        LDSU[SE_O + wr128[i]] = bf16r(ar[i]);
      }
    }
    __syncthreads();
    // g2: second layers; waves 0-3 -> u gate, waves 4-7 -> r gate
    f32x4 rr = {0.f,0.f,0.f,0.f};
    {
      f32x4 acc = {0.f,0.f,0.f,0.f};
      const int srcO = isMean ? SB_O : SE_O;
      const int pb   = isMean ? OFF_WU2 : OFF_WR2;
#pragma unroll
      for (int ks = 0; ks < 4; ++ks)
        acc = mfma16(ldsA(LDSU, srcO + a128[ks]), load_bfrag(pack + pb, 4*(w & 3) + ks, lane), acc);
      if (isMean){
#pragma unroll
        for (int i = 0; i < 4; ++i){ u[i] = fast_sigmoid(acc[i] + g2b); FUR[FU_O + furi[i]] = u[i]; }
      } else {
#pragma unroll
        for (int i = 0; i < 4; ++i){ rr[i] = fast_sigmoid(acc[i] + g2b); FUR[FR_O + furi[i]] = rr[i]; }
      }
    }
    // mask loads (latency hidden over g3/g4)
    f32x4 mk;
#pragma unroll
    for (int i = 0; i < 4; ++i) mk[i] = mtr[(rowBase + rb + i) * T_LEN + tj];
    __syncthreads();
    // g3: gated state yc -> SGH/SGL
    {
      f32x4 yc;
      if (isMean){
#pragma unroll
        for (int i = 0; i < 4; ++i){ float r_ = FUR[FR_O + furi[i]]; yc[i] = y0[i] * r_; }
      } else {
#pragma unroll
        for (int i = 0; i < 4; ++i){ u[i] = FUR[FU_O + furi[i]]; yc[i] = st[i] * rr[i]; }
      }
#pragma unroll
      for (int i = 0; i < 4; ++i){
        unsigned short hi = bf16r(yc[i]);
        LDSU[SGH_O + wr128[i]] = hi;
        LDSU[SGL_O + wr128[i]] = bf16r(yc[i] - bf16tof(hi));
      }
    }
    __syncthreads();
    // g4: n first layer
    {
      f32x4 an = {0.f,0.f,0.f,0.f};
#pragma unroll
      for (int ks = 0; ks < 4; ++ks){
        bf16x8 ah = ldsA(LDSU, SGH_O + a128[ks]);
        bf16x8 al = ldsA(LDSU, SGL_O + a128[ks]);
        bf16x8 bn = load_bfrag(pack + OFF_WN1, 4*w + ks, lane);
        an = mfma16(al, bn, an); an = mfma16(ah, bn, an);
      }
#pragma unroll
      for (int i = 0; i < 4; ++i) an[i] = fast_tanh(an[i] + bn1c + xr[i] * wn1L);
#pragma unroll
      for (int i = 0; i < 4; ++i) LDSU[SB_O + wr128[i]] = bf16r(an[i]);
    }
    __syncthreads();
    // g5: n second layer + blend + write next yin
    {
      f32x4 ns = {0.f,0.f,0.f,0.f};
#pragma unroll
      for (int ks = 0; ks < 4; ++ks)
        ns = mfma16(ldsA(LDSU, SB_O + a128[ks]), load_bfrag(pack + OFF_WN2, 4*w + ks, lane), ns);
#pragma unroll
      for (int i = 0; i < 4; ++i){
        float nv = ns[i] + bn2c;
        float uu = u[i];
        float base = isMean ? y0[i] : st[i];
        float nm = (1.0f - uu) * nv + uu * base;
        float fs = mk[i] * nm + (1.0f - mk[i]) * base;
        st[i] = isMean ? fs : fabsf(fs);
      }
      if (isMean){
#pragma unroll
        for (int i = 0; i < 4; ++i) LDSU[SA_O + wr64[i]] = bf16r(st[i]);
      }
    }
  }

  // ---------------- store (mean rows 0..524287, std after) ----------------
#pragma unroll
  for (int i = 0; i < 4; ++i){
    int r = rowBase + rb + i;
    if (isMean) out[r * 64 + c64] = st[i];
    else        out[524288 + r * 64 + c64] = st[i];
  }
}

extern "C" void kernel_launch(void* const* d_in, const int* in_sizes, int n_in,
                              void* d_out, int out_size, void* d_ws, size_t ws_size,
                              hipStream_t stream)
{
  (void)in_sizes; (void)n_in; (void)out_size; (void)ws_size;
  unsigned short* pack = (unsigned short*)d_ws;
  prep_pack<<<dim3(PACK_TOT / 256), dim3(256), 0, stream>>>(
      (const float*)d_in[2],  (const float*)d_in[4],  (const float*)d_in[6],
      (const float*)d_in[8],  (const float*)d_in[12], (const float*)d_in[16],
      (const float*)d_in[10], (const float*)d_in[14], (const float*)d_in[18],
      pack);
  ode_rnn_main<<<dim3(512), dim3(512), 0, stream>>>(
      (const float*)d_in[0],  (const float*)d_in[1],
      (const float*)d_in[3],  (const float*)d_in[5],  (const float*)d_in[7],
      (const float*)d_in[9],  (const float*)d_in[11],
      (const float*)d_in[13], (const float*)d_in[15],
      (const float*)d_in[17], (const float*)d_in[19],
      (const float*)d_in[8],  (const float*)d_in[12], (const float*)d_in[16],
      (const unsigned short*)pack, (float*)d_out);
}

// Round 3
// 9907.198 us; speedup vs baseline: 1.1755x; 1.1145x over previous
//
#include <hip/hip_runtime.h>

typedef __attribute__((ext_vector_type(8))) short bf16x8;
typedef __attribute__((ext_vector_type(4))) float f32x4;

#define T_LEN 256
// pack offsets (short units)
#define OFF_W1   0
#define OFF_W2   8192
#define OFF_W31  24576
#define OFF_W3   40960
#define OFF_WU1  49152
#define OFF_WR1  65536
#define OFF_WN1  81920
#define OFF_WU2  98304
#define OFF_WR2  106496
#define OFF_WN2  114688
#define OFF_B3W1 131072   // f32[128] appended after bf16 packs
#define PREP_TOT 131200

// LDS layout (short units)
#define HA_O   0      // act buffer A [16][128]
#define HB_O   2048   // act buffer B [16][128]; first 1024 doubles as st [16][64]
#define SGH_O  4096   // state hi / Gsum lo [16][128]
#define SGL_O  6144   // state lo [16][128]
#define FU_F   4096   // float-index: u gate f32 [16][64]
#define FR_F   5120   // float-index: r gate f32 [16][64]
#define LDS_SHORTS 12288

__device__ __forceinline__ unsigned short bf16r(float f){
  unsigned int x = __builtin_bit_cast(unsigned int, f);
  unsigned int r = (x + 0x7FFFu + ((x >> 16) & 1u)) >> 16;
  return (unsigned short)r;
}
__device__ __forceinline__ float bf16tof(unsigned short u){
  unsigned int v = ((unsigned int)u) << 16;
  return __builtin_bit_cast(float, v);
}
__device__ __forceinline__ float fast_tanh(float x){
  float e = __builtin_amdgcn_exp2f(x * 2.885390081777927f);   // exp(2x)
  return 1.0f - 2.0f * __builtin_amdgcn_rcpf(1.0f + e);
}
__device__ __forceinline__ float fast_sigmoid(float x){
  float e = __builtin_amdgcn_exp2f(x * -1.4426950408889634f); // exp(-x)
  return __builtin_amdgcn_rcpf(1.0f + e);
}
__device__ __forceinline__ f32x4 mfma16(bf16x8 a, bf16x8 b, f32x4 c){
  return __builtin_amdgcn_mfma_f32_16x16x32_bf16(a, b, c, 0, 0, 0);
}
__device__ __forceinline__ bf16x8 load_bfrag(const unsigned short* p, int blk, int lane){
  return *reinterpret_cast<const bf16x8*>(p + ((blk << 6) + lane) * 8);
}
__device__ __forceinline__ bf16x8 ldsA(const unsigned short* LDSU, int idx){
  return *reinterpret_cast<const bf16x8*>(LDSU + idx);
}

// Pack weights to bf16 MFMA B-fragment order; compute W31=W3@W1, b3W1=b3@W1.
__global__ void prep_pack(const float* __restrict__ W1, const float* __restrict__ W2,
                          const float* __restrict__ W3, const float* __restrict__ Wu1,
                          const float* __restrict__ Wr1, const float* __restrict__ Wn1,
                          const float* __restrict__ Wu2, const float* __restrict__ Wr2,
                          const float* __restrict__ Wn2, const float* __restrict__ b3,
                          unsigned short* __restrict__ pack)
{
  int e = blockIdx.x * blockDim.x + threadIdx.x;
  if (e >= PREP_TOT) return;
  if (e >= OFF_B3W1){
    int j = e - OFF_B3W1;           // 0..127
    float s = 0.0f;
    for (int mm = 0; mm < 64; ++mm) s += b3[mm] * W1[mm * 128 + j];
    ((float*)(pack + OFF_B3W1))[j] = s;
    return;
  }
  const int offs[11] = {0, 8192, 24576, 40960, 49152, 65536, 81920, 98304, 106496, 114688, 131072};
  const int Ks[10] = {64,128,128,128,128,128,128,128,128,128};
  const int Ns[10] = {128,128,128,64,128,128,128,64,64,128};
  int m = 0;
  while (e >= offs[m + 1]) ++m;
  int el = e - offs[m];
  int j = el & 7, lane = (el >> 3) & 63, blk = el >> 9;
  int ksteps = Ks[m] >> 5;
  int ks = blk % ksteps, nt = blk / ksteps;
  int k = ks * 32 + ((lane >> 4) << 3) + j;
  int n = nt * 16 + (lane & 15);
  float v;
  if (m == 2){ // W31[k][n] = sum_mm W3[k][mm] * W1[mm][n]
    float s = 0.0f;
    for (int mm = 0; mm < 64; ++mm) s += W3[k * 64 + mm] * W1[mm * 128 + n];
    v = s;
  } else {
    const float* srcs[10] = {W1, W2, nullptr, W3, Wu1, Wr1, Wn1, Wu2, Wr2, Wn2};
    v = srcs[m][k * Ns[m] + n];
  }
  pack[e] = bf16r(v);
}

__global__ __launch_bounds__(512, 4) void ode_rnn_main(
  const float* __restrict__ bts, const float* __restrict__ mtr,
  const float* __restrict__ b1, const float* __restrict__ b2, const float* __restrict__ b3,
  const float* __restrict__ bu1, const float* __restrict__ bu2,
  const float* __restrict__ br1, const float* __restrict__ br2,
  const float* __restrict__ bn1, const float* __restrict__ bn2,
  const float* __restrict__ Wu1f, const float* __restrict__ Wr1f, const float* __restrict__ Wn1f,
  const unsigned short* __restrict__ pack, float* __restrict__ out)
{
  __shared__ __align__(16) unsigned short LDSU[LDS_SHORTS];
  float* FUR = (float*)LDSU;
  const int tid = threadIdx.x, w = tid >> 6, lane = tid & 63;
  const int arow = lane & 15, g = lane >> 4, rb = g << 2;
  const int c128 = (w << 4) + arow;        // wave's 128-wide column (== state column)
  const int c64  = ((w & 3) << 4) + arow;  // wave's 64-wide column
  const bool isMean = (w < 4);
  const int rowBase = blockIdx.x * 16;

  // precomputed LDS indices (short units)
  int a128[4], wr128[4], wr64[4], furi[4], a64v[2];
#pragma unroll
  for (int ks = 0; ks < 4; ++ks) a128[ks] = arow*128 + ((32*ks + 8*g) ^ (arow << 3));
#pragma unroll
  for (int ks = 0; ks < 2; ++ks) a64v[ks] = arow*64 + ((32*ks + 8*g) ^ ((arow & 7) << 3));
#pragma unroll
  for (int i = 0; i < 4; ++i){
    int r = rb + i;
    wr128[i] = r*128 + (c128 ^ (r << 3));
    wr64[i]  = r*64  + (c64 ^ ((r & 7) << 3));
    furi[i]  = r*64 + c64;
  }

  // persistent per-wave weight fragments
  bf16x8 w1f[2], w2f[4], w31f[4];
#pragma unroll
  for (int ks = 0; ks < 2; ++ks) w1f[ks]  = load_bfrag(pack + OFF_W1,  2*w + ks, lane);
#pragma unroll
  for (int ks = 0; ks < 4; ++ks) w2f[ks]  = load_bfrag(pack + OFF_W2,  4*w + ks, lane);
#pragma unroll
  for (int ks = 0; ks < 4; ++ks) w31f[ks] = load_bfrag(pack + OFF_W31, 4*w + ks, lane);

  const float* b3w1p = (const float*)(pack + OFF_B3W1);
  const float b1c = b1[c128], b2c = b2[c128], b3c = b3[c64], b3w1c = b3w1p[c128];
  const float bu1c = bu1[c128], br1c = br1[c128], bn1c = bn1[c128], bn2c = bn2[c128];
  const float g2b = isMean ? bu2[c64] : br2[c64];
  const float wu1L = Wu1f[16384 + c128], wr1L = Wr1f[16384 + c128], wn1L = Wn1f[16384 + c128];

  // zero st buffer (HB[0:2048])
  ((unsigned long long*)(LDSU + HB_O))[tid] = 0ULL;
  __syncthreads();

  f32x4 st = {0.f,0.f,0.f,0.f};   // w<4: mean state; w>=4: std state
  f32x4 R  = {0.f,0.f,0.f,0.f};   // y@W1 + b1 (recurrent, fp32)
  f32x4 yf = {0.f,0.f,0.f,0.f};   // mean_ode (mean waves)
  f32x4 u  = {0.f,0.f,0.f,0.f};

#pragma unroll 1
  for (int s = 0; s < T_LEN; ++s){
    const int tj = T_LEN - 1 - s;
    const float t1 = bts[2*tj];
    const float t0 = (s == 0) ? 5.0f : bts[2*tj + 2];
    const float hh = (t1 - t0) * 0.125f;

    f32x4 xr;
#pragma unroll
    for (int i = 0; i < 4; ++i) xr[i] = bts[((rowBase + rb + i) * T_LEN + tj) * 2 + 1];

    f32x4 Gsum = {0.f,0.f,0.f,0.f};
    f32x4 Hsum;

    // ---------------- RK4: 8 substeps x 8 phases ----------------
#pragma unroll 1
    for (int ss = 0; ss < 8; ++ss){
      // ---- p0: h1_1 (+ R recurrence) ----
      {
        f32x4 acc;
        if (ss == 0){
          acc = (f32x4){b1c, b1c, b1c, b1c};
          acc = mfma16(ldsA(LDSU, HB_O + a64v[0]), w1f[0], acc);
          acc = mfma16(ldsA(LDSU, HB_O + a64v[1]), w1f[1], acc);
        } else {
#pragma unroll
          for (int i = 0; i < 4; ++i) acc[i] = R[i] + hh * b3w1c;
#pragma unroll
          for (int ks = 0; ks < 4; ++ks)
            acc = mfma16(ldsA(LDSU, HB_O + a128[ks]), w31f[ks], acc);
        }
        R = acc;
        f32x4 h;
#pragma unroll
        for (int i = 0; i < 4; ++i) h[i] = fast_tanh(acc[i]);
#pragma unroll
        for (int i = 0; i < 4; ++i) LDSU[HA_O + wr128[i]] = bf16r(h[i]);
      }
      __syncthreads();
      // ---- p1/p3/p5: h2 stages 1..3 ----
#pragma unroll
      for (int hs = 0; hs < 3; ++hs){
        const float wgt = (hs == 0) ? 1.0f : 2.0f;
        const float scn = (hs == 2) ? hh : 0.5f * hh;
        f32x4 acc = (f32x4){b2c, b2c, b2c, b2c};
#pragma unroll
        for (int ks = 0; ks < 4; ++ks)
          acc = mfma16(ldsA(LDSU, HA_O + a128[ks]), w2f[ks], acc);
        f32x4 h;
#pragma unroll
        for (int i = 0; i < 4; ++i) h[i] = fast_tanh(acc[i]);
        if (hs == 0) Hsum = h;
        else {
#pragma unroll
          for (int i = 0; i < 4; ++i) Hsum[i] += wgt * h[i];
        }
#pragma unroll
        for (int i = 0; i < 4; ++i) LDSU[HB_O + wr128[i]] = bf16r(h[i] * scn);
        __syncthreads();
        // ---- p2/p4/p6: h1 stages 2..4 ----
        const float ac = (hs == 2) ? hh : 0.5f * hh;
        f32x4 acc2;
#pragma unroll
        for (int i = 0; i < 4; ++i) acc2[i] = R[i] + ac * b3w1c;
#pragma unroll
        for (int ks = 0; ks < 4; ++ks)
          acc2 = mfma16(ldsA(LDSU, HB_O + a128[ks]), w31f[ks], acc2);
        f32x4 h1v;
#pragma unroll
        for (int i = 0; i < 4; ++i) h1v[i] = fast_tanh(acc2[i]);
#pragma unroll
        for (int i = 0; i < 4; ++i) LDSU[HA_O + wr128[i]] = bf16r(h1v[i]);
        __syncthreads();
      }
      // ---- p7: h2_4, Hsum/Gsum finalize ----
      {
        f32x4 acc = (f32x4){b2c, b2c, b2c, b2c};
#pragma unroll
        for (int ks = 0; ks < 4; ++ks)
          acc = mfma16(ldsA(LDSU, HA_O + a128[ks]), w2f[ks], acc);
        f32x4 h;
#pragma unroll
        for (int i = 0; i < 4; ++i){ h[i] = fast_tanh(acc[i]); Hsum[i] += h[i]; Gsum[i] += Hsum[i]; }
        const float sc6 = hh * (1.0f / 6.0f);
        if (ss < 7){
#pragma unroll
          for (int i = 0; i < 4; ++i) LDSU[HB_O + wr128[i]] = bf16r(Hsum[i] * sc6);
        } else {
#pragma unroll
          for (int i = 0; i < 4; ++i){
            float gv = Gsum[i] * sc6;
            unsigned short hi = bf16r(gv);
            LDSU[HB_O  + wr128[i]] = hi;
            LDSU[SGH_O + wr128[i]] = bf16r(gv - bf16tof(hi));
          }
        }
      }
      __syncthreads();
    }

    // ---------------- phase Y: recover mean_ode (mean waves) ----------------
    if (isMean){
      bf16x8 w3f[4];
#pragma unroll
      for (int ks = 0; ks < 4; ++ks) w3f[ks] = load_bfrag(pack + OFF_W3, 4*w + ks, lane);
      f32x4 acc = {0.f,0.f,0.f,0.f};
#pragma unroll
      for (int ks = 0; ks < 4; ++ks) acc = mfma16(ldsA(LDSU, HB_O  + a128[ks]), w3f[ks], acc);
#pragma unroll
      for (int ks = 0; ks < 4; ++ks) acc = mfma16(ldsA(LDSU, SGH_O + a128[ks]), w3f[ks], acc);
#pragma unroll
      for (int i = 0; i < 4; ++i) yf[i] = st[i] + acc[i] + 8.0f * hh * b3c;
    }
    __syncthreads();
    // ---------------- phase Y2: write state hi/lo ----------------
    {
      f32x4 sv = isMean ? yf : st;
#pragma unroll
      for (int i = 0; i < 4; ++i){
        unsigned short hi = bf16r(sv[i]);
        LDSU[SGH_O + wr128[i]] = hi;
        LDSU[SGL_O + wr128[i]] = bf16r(sv[i] - bf16tof(hi));
      }
    }
    __syncthreads();
    // ---------------- GRU ----------------
    // g1: u & r first layers
    {
      f32x4 au = {0.f,0.f,0.f,0.f}, ar = {0.f,0.f,0.f,0.f};
#pragma unroll
      for (int ks = 0; ks < 4; ++ks){
        bf16x8 ah = ldsA(LDSU, SGH_O + a128[ks]);
        bf16x8 al = ldsA(LDSU, SGL_O + a128[ks]);
        bf16x8 bu = load_bfrag(pack + OFF_WU1, 4*w + ks, lane);
        bf16x8 br_ = load_bfrag(pack + OFF_WR1, 4*w + ks, lane);
        au = mfma16(al, bu, au);  au = mfma16(ah, bu, au);
        ar = mfma16(al, br_, ar); ar = mfma16(ah, br_, ar);
      }
#pragma unroll
      for (int i = 0; i < 4; ++i){
        au[i] = fast_tanh(au[i] + bu1c + xr[i] * wu1L);
        ar[i] = fast_tanh(ar[i] + br1c + xr[i] * wr1L);
      }
#pragma unroll
      for (int i = 0; i < 4; ++i){
        LDSU[HA_O + wr128[i]] = bf16r(au[i]);
        LDSU[HB_O + wr128[i]] = bf16r(ar[i]);
      }
    }
    __syncthreads();
    // g2: second layers (mean->u, std->r)
    f32x4 rr = {0.f,0.f,0.f,0.f};
    {
      f32x4 acc = {0.f,0.f,0.f,0.f};
      const int srcO = isMean ? HA_O : HB_O;
      const int pb   = isMean ? OFF_WU2 : OFF_WR2;
#pragma unroll
      for (int ks = 0; ks < 4; ++ks)
        acc = mfma16(ldsA(LDSU, srcO + a128[ks]), load_bfrag(pack + pb, 4*(w & 3) + ks, lane), acc);
      if (isMean){
#pragma unroll
        for (int i = 0; i < 4; ++i){ u[i] = fast_sigmoid(acc[i] + g2b); FUR[FU_F + furi[i]] = u[i]; }
      } else {
#pragma unroll
        for (int i = 0; i < 4; ++i){ rr[i] = fast_sigmoid(acc[i] + g2b); FUR[FR_F + furi[i]] = rr[i]; }
      }
    }
    f32x4 mk;
#pragma unroll
    for (int i = 0; i < 4; ++i) mk[i] = mtr[(rowBase + rb + i) * T_LEN + tj];
    __syncthreads();
    // g3: gated state -> SGH/SGL
    {
      f32x4 yc;
      if (isMean){
#pragma unroll
        for (int i = 0; i < 4; ++i){ float r_ = FUR[FR_F + furi[i]]; yc[i] = yf[i] * r_; }
      } else {
#pragma unroll
        for (int i = 0; i < 4; ++i){ u[i] = FUR[FU_F + furi[i]]; yc[i] = st[i] * rr[i]; }
      }
#pragma unroll
      for (int i = 0; i < 4; ++i){
        unsigned short hi = bf16r(yc[i]);
        LDSU[SGH_O + wr128[i]] = hi;
        LDSU[SGL_O + wr128[i]] = bf16r(yc[i] - bf16tof(hi));
      }
    }
    __syncthreads();
    // g4: n first layer
    {
      f32x4 an = {0.f,0.f,0.f,0.f};
#pragma unroll
      for (int ks = 0; ks < 4; ++ks){
        bf16x8 ah = ldsA(LDSU, SGH_O + a128[ks]);
        bf16x8 al = ldsA(LDSU, SGL_O + a128[ks]);
        bf16x8 bn = load_bfrag(pack + OFF_WN1, 4*w + ks, lane);
        an = mfma16(al, bn, an); an = mfma16(ah, bn, an);
      }
#pragma unroll
      for (int i = 0; i < 4; ++i) an[i] = fast_tanh(an[i] + bn1c + xr[i] * wn1L);
#pragma unroll
      for (int i = 0; i < 4; ++i) LDSU[HA_O + wr128[i]] = bf16r(an[i]);
    }
    __syncthreads();
    // g5: n second layer + blend + write st for next step
    {
      f32x4 ns = {0.f,0.f,0.f,0.f};
#pragma unroll
      for (int ks = 0; ks < 4; ++ks)
        ns = mfma16(ldsA(LDSU, HA_O + a128[ks]), load_bfrag(pack + OFF_WN2, 4*w + ks, lane), ns);
#pragma unroll
      for (int i = 0; i < 4; ++i){
        float nv = ns[i] + bn2c;
        float uu = u[i];
        float base = isMean ? yf[i] : st[i];
        float nm = (1.0f - uu) * nv + uu * base;
        float fs = mk[i] * nm + (1.0f - mk[i]) * base;
        st[i] = isMean ? fs : fabsf(fs);
      }
      if (isMean){
#pragma unroll
        for (int i = 0; i < 4; ++i) LDSU[HB_O + wr64[i]] = bf16r(st[i]);
      }
    }
    __syncthreads();
  }

  // ---------------- store ----------------
#pragma unroll
  for (int i = 0; i < 4; ++i){
    int r = rowBase + rb + i;
    if (isMean) out[r * 64 + c64] = st[i];
    else        out[524288 + r * 64 + c64] = st[i];
  }
}

extern "C" void kernel_launch(void* const* d_in, const int* in_sizes, int n_in,
                              void* d_out, int out_size, void* d_ws, size_t ws_size,
                              hipStream_t stream)
{
  (void)in_sizes; (void)n_in; (void)out_size; (void)ws_size;
  unsigned short* pack = (unsigned short*)d_ws;
  prep_pack<<<dim3((PREP_TOT + 255) / 256), dim3(256), 0, stream>>>(
      (const float*)d_in[2],  (const float*)d_in[4],  (const float*)d_in[6],
      (const float*)d_in[8],  (const float*)d_in[12], (const float*)d_in[16],
      (const float*)d_in[10], (const float*)d_in[14], (const float*)d_in[18],
      (const float*)d_in[7],  pack);
  ode_rnn_main<<<dim3(512), dim3(512), 0, stream>>>(
      (const float*)d_in[0],  (const float*)d_in[1],
      (const float*)d_in[3],  (const float*)d_in[5],  (const float*)d_in[7],
      (const float*)d_in[9],  (const float*)d_in[11],
      (const float*)d_in[13], (const float*)d_in[15],
      (const float*)d_in[17], (const float*)d_in[19],
      (const float*)d_in[8],  (const float*)d_in[12], (const float*)d_in[16],
      (const unsigned short*)pack, (float*)d_out);
}